// Round 7
// baseline (27.660 us; speedup 1.0000x reference)
//
#include <hip/hip_runtime.h>

typedef float float4v __attribute__((ext_vector_type(4)));

#define BLOCK 256

// ---- tiny not-a-knot spline solve (tridiagonal -> Thomas), n = 10 ----
// SoA float2 tables: s32[i]={a3,a2}, s10[i]={a1,a0}; sm={scale,off} for the
// uniform-knot analytic interval index i = clamp(int(x*scale+off),0,8).
__device__ __forceinline__ void spline_setup(const float* __restrict__ points,
                                             const float* __restrict__ values,
                                             float2* s32, float2* s10, float* sm)
{
    float p[10], v[10];
#pragma unroll
    for (int k = 0; k < 10; ++k) { p[k] = points[k]; v[k] = values[k]; }
    float dx[9], sl[9];
#pragma unroll
    for (int k = 0; k < 9; ++k) { dx[k] = p[k + 1] - p[k]; sl[k] = (v[k + 1] - v[k]) / dx[k]; }

    float dg[10], lo[10], up[10], bb[10];
    float d0 = p[2] - p[0];
    dg[0] = dx[1]; up[0] = d0; lo[0] = 0.0f;
    bb[0] = ((dx[0] + 2.0f * d0) * dx[1] * sl[0] + dx[0] * dx[0] * sl[1]) / d0;
#pragma unroll
    for (int i = 1; i <= 8; ++i) {
        lo[i] = dx[i];
        dg[i] = 2.0f * (dx[i - 1] + dx[i]);
        up[i] = dx[i - 1];
        bb[i] = 3.0f * (dx[i] * sl[i - 1] + dx[i - 1] * sl[i]);
    }
    float dn = p[9] - p[7];
    lo[9] = dn; dg[9] = dx[7]; up[9] = 0.0f;
    bb[9] = (dx[8] * dx[8] * sl[7] + (2.0f * dn + dx[8]) * dx[7] * sl[8]) / dn;

    float cp[10], bp[10];
    cp[0] = up[0] / dg[0];
    bp[0] = bb[0] / dg[0];
#pragma unroll
    for (int i = 1; i <= 9; ++i) {
        float m = dg[i] - lo[i] * cp[i - 1];
        cp[i] = up[i] / m;
        bp[i] = (bb[i] - lo[i] * bp[i - 1]) / m;
    }
    float s[10];
    s[9] = bp[9];
#pragma unroll
    for (int i = 8; i >= 0; --i) s[i] = bp[i] - cp[i] * s[i + 1];

#pragma unroll
    for (int i = 0; i < 9; ++i) {
        float tt = (s[i] + s[i + 1] - 2.0f * sl[i]) / dx[i];
        float c3 = tt / dx[i];
        float c2 = (sl[i] - s[i]) / dx[i] - tt;
        float c1 = s[i];
        float c0 = v[i];
        float pi = p[i];
        float a3 = c3;
        float a2 = c2 - 3.0f * c3 * pi;
        float a1 = (3.0f * c3 * pi - 2.0f * c2) * pi + c1;
        float a0 = ((-c3 * pi + c2) * pi - c1) * pi + c0;
        s32[i] = make_float2(a3, a2);
        s10[i] = make_float2(a1, a0);
    }
    float scale = 9.0f / (p[9] - p[0]);
    sm[0] = scale;
    sm[1] = -p[0] * scale;
}

__device__ __forceinline__ float eval_one(float xx, float scale, float off,
                                          const float2* s32, const float2* s10)
{
    int i = (int)(xx * scale + off);   // trunc == floor in-range; clamp fixes edges
    i = i < 0 ? 0 : (i > 8 ? 8 : i);
    float2 h = s32[i];
    float2 l = s10[i];
    return ((h.x * xx + h.y) * xx + l.x) * xx + l.y;
}

// Exact-fit path: n4 == gridDim.x * BLOCK * TRIPS.
// 4-deep software pipeline: rotating 4-slot register buffer, fully unrolled
// (all indices static). Only slot 0 is loaded before the setup barrier so the
// setup waitcnt (ordered vmcnt!) drains a single load; slots 1..3 issue right
// after; steady-state prefetches trip k+4 BEFORE compute/store of trip k.
template <int TRIPS>
__global__ __launch_bounds__(BLOCK) void spline_eval_pipe(
    const float* __restrict__ xin,
    const float* __restrict__ points,
    const float* __restrict__ values,
    float* __restrict__ out)
{
    static_assert(TRIPS >= 4, "pipeline depth 4");
    __shared__ float2 s32[9];
    __shared__ float2 s10[9];
    __shared__ float sm[2];

    const float4v* __restrict__ x4 = (const float4v*)xin;
    float4v* __restrict__ o4 = (float4v*)out;

    const int stride = gridDim.x * BLOCK;
    const int base = blockIdx.x * BLOCK + threadIdx.x;

    float4v buf[4];
    buf[0] = x4[base];                     // in flight across setup

    if (threadIdx.x == 0) spline_setup(points, values, s32, s10, sm);
    __syncthreads();

    buf[1] = x4[base + 1 * stride];
    buf[2] = x4[base + 2 * stride];
    buf[3] = x4[base + 3 * stride];

    const float scale = sm[0], off = sm[1];

#pragma unroll
    for (int k = 0; k < TRIPS; ++k) {
        float4v cur = buf[k & 3];          // static index (unrolled)
        if (k + 4 < TRIPS)
            buf[k & 3] = x4[base + (k + 4) * stride];   // prefetch depth 4
        float4v yv;
#pragma unroll
        for (int j = 0; j < 4; ++j)
            yv[j] = eval_one(cur[j], scale, off, s32, s10);
        o4[base + k * stride] = yv;
    }
}

// Generic fallback: rolling grid-stride + scalar tail.
__global__ __launch_bounds__(BLOCK) void spline_eval_generic(
    const float* __restrict__ xin,
    const float* __restrict__ points,
    const float* __restrict__ values,
    float* __restrict__ out,
    int n4, int total)
{
    __shared__ float2 s32[9];
    __shared__ float2 s10[9];
    __shared__ float sm[2];

    if (threadIdx.x == 0) spline_setup(points, values, s32, s10, sm);
    __syncthreads();

    const float scale = sm[0], off = sm[1];

    const float4v* __restrict__ x4 = (const float4v*)xin;
    float4v* __restrict__ o4 = (float4v*)out;

    int idx = blockIdx.x * blockDim.x + threadIdx.x;
    int stride = gridDim.x * blockDim.x;

    for (int vi = idx; vi < n4; vi += stride) {
        float4v xv = x4[vi];
        float4v yv;
#pragma unroll
        for (int j = 0; j < 4; ++j)
            yv[j] = eval_one(xv[j], scale, off, s32, s10);
        o4[vi] = yv;
    }

    int tail = n4 * 4;
    if (blockIdx.x == 0) {
        for (int e = tail + threadIdx.x; e < total; e += blockDim.x) {
            out[e] = eval_one(xin[e], scale, off, s32, s10);
        }
    }
}

extern "C" void kernel_launch(void* const* d_in, const int* in_sizes, int n_in,
                              void* d_out, int out_size, void* d_ws, size_t ws_size,
                              hipStream_t stream) {
    const float* x = (const float*)d_in[0];
    const float* points = (const float*)d_in[1];
    const float* values = (const float*)d_in[2];
    float* out = (float*)d_out;

    int total = out_size;              // 4096*4096 = 16777216
    int n4 = total / 4;

    const int TRIPS = 8;
    const int grid = 2048;             // 8 blocks/CU

    if (total % 4 == 0 && n4 == grid * BLOCK * TRIPS) {
        spline_eval_pipe<TRIPS><<<grid, BLOCK, 0, stream>>>(x, points, values, out);
    } else {
        spline_eval_generic<<<grid, BLOCK, 0, stream>>>(x, points, values, out, n4, total);
    }
}

// Round 8
// 27.390 us; speedup vs baseline: 1.0098x; 1.0098x over previous
//
#include <hip/hip_runtime.h>

typedef float float4v __attribute__((ext_vector_type(4)));

#define BLOCK 256

// ---- tiny not-a-knot spline solve (tridiagonal -> Thomas), n = 10 ----
// SoA float2 tables: s32[i]={a3,a2}, s10[i]={a1,a0}; sm={scale,off} for the
// uniform-knot analytic interval index i = clamp(int(x*scale+off),0,8).
__device__ __forceinline__ void spline_setup(const float* __restrict__ points,
                                             const float* __restrict__ values,
                                             float2* s32, float2* s10, float* sm)
{
    float p[10], v[10];
#pragma unroll
    for (int k = 0; k < 10; ++k) { p[k] = points[k]; v[k] = values[k]; }
    float dx[9], sl[9];
#pragma unroll
    for (int k = 0; k < 9; ++k) { dx[k] = p[k + 1] - p[k]; sl[k] = (v[k + 1] - v[k]) / dx[k]; }

    float dg[10], lo[10], up[10], bb[10];
    float d0 = p[2] - p[0];
    dg[0] = dx[1]; up[0] = d0; lo[0] = 0.0f;
    bb[0] = ((dx[0] + 2.0f * d0) * dx[1] * sl[0] + dx[0] * dx[0] * sl[1]) / d0;
#pragma unroll
    for (int i = 1; i <= 8; ++i) {
        lo[i] = dx[i];
        dg[i] = 2.0f * (dx[i - 1] + dx[i]);
        up[i] = dx[i - 1];
        bb[i] = 3.0f * (dx[i] * sl[i - 1] + dx[i - 1] * sl[i]);
    }
    float dn = p[9] - p[7];
    lo[9] = dn; dg[9] = dx[7]; up[9] = 0.0f;
    bb[9] = (dx[8] * dx[8] * sl[7] + (2.0f * dn + dx[8]) * dx[7] * sl[8]) / dn;

    float cp[10], bp[10];
    cp[0] = up[0] / dg[0];
    bp[0] = bb[0] / dg[0];
#pragma unroll
    for (int i = 1; i <= 9; ++i) {
        float m = dg[i] - lo[i] * cp[i - 1];
        cp[i] = up[i] / m;
        bp[i] = (bb[i] - lo[i] * bp[i - 1]) / m;
    }
    float s[10];
    s[9] = bp[9];
#pragma unroll
    for (int i = 8; i >= 0; --i) s[i] = bp[i] - cp[i] * s[i + 1];

#pragma unroll
    for (int i = 0; i < 9; ++i) {
        float tt = (s[i] + s[i + 1] - 2.0f * sl[i]) / dx[i];
        float c3 = tt / dx[i];
        float c2 = (sl[i] - s[i]) / dx[i] - tt;
        float c1 = s[i];
        float c0 = v[i];
        float pi = p[i];
        float a3 = c3;
        float a2 = c2 - 3.0f * c3 * pi;
        float a1 = (3.0f * c3 * pi - 2.0f * c2) * pi + c1;
        float a0 = ((-c3 * pi + c2) * pi - c1) * pi + c0;
        s32[i] = make_float2(a3, a2);
        s10[i] = make_float2(a1, a0);
    }
    float scale = 9.0f / (p[9] - p[0]);
    sm[0] = scale;
    sm[1] = -p[0] * scale;
}

// cold-path (rare: u < 4) full-range LDS gather evaluation
__device__ __forceinline__ float eval_lds(float xx, float u,
                                          const float2* s32, const float2* s10)
{
    int i = (int)u;
    i = i < 0 ? 0 : (i > 8 ? 8 : i);
    float2 h = s32[i];
    float2 l = s10[i];
    return ((h.x * xx + h.y) * xx + l.x) * xx + l.y;
}

// Exact-fit path: n4 == gridDim.x * BLOCK * TRIPS. R6 depth-2 rolling
// pipeline. Hot path: intervals 4..8 held in REGISTERS, selected by a
// 4-level cndmask ladder on u = x*scale+off — zero LDS in the hot loop.
// Lanes with u < 4 (never taken for x in [0,1)) fall back to the LDS
// gather under an exec-masked branch, preserving full-range correctness.
template <int TRIPS>
__global__ __launch_bounds__(BLOCK) void spline_eval_pipe(
    const float* __restrict__ xin,
    const float* __restrict__ points,
    const float* __restrict__ values,
    float* __restrict__ out)
{
    __shared__ float2 s32[9];
    __shared__ float2 s10[9];
    __shared__ float sm[2];

    const float4v* __restrict__ x4 = (const float4v*)xin;
    float4v* __restrict__ o4 = (float4v*)out;

    const int stride = gridDim.x * BLOCK;
    const int base = blockIdx.x * BLOCK + threadIdx.x;

    float4v cur = x4[base];            // in flight across setup

    if (threadIdx.x == 0) spline_setup(points, values, s32, s10, sm);
    __syncthreads();

    const float scale = sm[0], off = sm[1];
    // hot register table: intervals 4..8 (x in [0,1) maps here)
    const float2 h4 = s32[4], h5 = s32[5], h6 = s32[6], h7 = s32[7], h8 = s32[8];
    const float2 l4 = s10[4], l5 = s10[5], l6 = s10[6], l7 = s10[7], l8 = s10[8];

    int vi = base;
#pragma unroll
    for (int k = 0; k < TRIPS; ++k) {
        float4v nxt;
        if (k + 1 < TRIPS) nxt = x4[vi + stride];   // depth-2 prefetch
        float4v yv;
        float uu[4];
#pragma unroll
        for (int j = 0; j < 4; ++j) {
            float xx = cur[j];
            float u = xx * scale + off;
            uu[j] = u;
            // 4-level select ladder over intervals 4..8 (pure VALU cndmask)
            float hx = h4.x, hy = h4.y, lx = l4.x, ly = l4.y;
            bool b5 = (u >= 5.0f), b6 = (u >= 6.0f), b7 = (u >= 7.0f), b8 = (u >= 8.0f);
            hx = b5 ? h5.x : hx;  hy = b5 ? h5.y : hy;  lx = b5 ? l5.x : lx;  ly = b5 ? l5.y : ly;
            hx = b6 ? h6.x : hx;  hy = b6 ? h6.y : hy;  lx = b6 ? l6.x : lx;  ly = b6 ? l6.y : ly;
            hx = b7 ? h7.x : hx;  hy = b7 ? h7.y : hy;  lx = b7 ? l7.x : lx;  ly = b7 ? l7.y : ly;
            hx = b8 ? h8.x : hx;  hy = b8 ? h8.y : hy;  lx = b8 ? l8.x : lx;  ly = b8 ? l8.y : ly;
            yv[j] = ((hx * xx + hy) * xx + lx) * xx + ly;
        }
        // cold fixup: any lane/element with u < 4 re-evaluates via LDS gather
        if (uu[0] < 4.0f || uu[1] < 4.0f || uu[2] < 4.0f || uu[3] < 4.0f) {
#pragma unroll
            for (int j = 0; j < 4; ++j)
                if (uu[j] < 4.0f) yv[j] = eval_lds(cur[j], uu[j], s32, s10);
        }
        o4[vi] = yv;
        vi += stride;
        cur = nxt;
    }
}

// Generic fallback: rolling grid-stride + scalar tail, full LDS path.
__global__ __launch_bounds__(BLOCK) void spline_eval_generic(
    const float* __restrict__ xin,
    const float* __restrict__ points,
    const float* __restrict__ values,
    float* __restrict__ out,
    int n4, int total)
{
    __shared__ float2 s32[9];
    __shared__ float2 s10[9];
    __shared__ float sm[2];

    if (threadIdx.x == 0) spline_setup(points, values, s32, s10, sm);
    __syncthreads();

    const float scale = sm[0], off = sm[1];

    const float4v* __restrict__ x4 = (const float4v*)xin;
    float4v* __restrict__ o4 = (float4v*)out;

    int idx = blockIdx.x * blockDim.x + threadIdx.x;
    int stride = gridDim.x * blockDim.x;

    for (int vi = idx; vi < n4; vi += stride) {
        float4v xv = x4[vi];
        float4v yv;
#pragma unroll
        for (int j = 0; j < 4; ++j) {
            float u = xv[j] * scale + off;
            yv[j] = eval_lds(xv[j], u, s32, s10);
        }
        o4[vi] = yv;
    }

    int tail = n4 * 4;
    if (blockIdx.x == 0) {
        for (int e = tail + threadIdx.x; e < total; e += blockDim.x) {
            float u = xin[e] * scale + off;
            out[e] = eval_lds(xin[e], u, s32, s10);
        }
    }
}

extern "C" void kernel_launch(void* const* d_in, const int* in_sizes, int n_in,
                              void* d_out, int out_size, void* d_ws, size_t ws_size,
                              hipStream_t stream) {
    const float* x = (const float*)d_in[0];
    const float* points = (const float*)d_in[1];
    const float* values = (const float*)d_in[2];
    float* out = (float*)d_out;

    int total = out_size;              // 4096*4096 = 16777216
    int n4 = total / 4;

    const int TRIPS = 8;
    const int grid = 2048;             // 8 blocks/CU

    if (total % 4 == 0 && n4 == grid * BLOCK * TRIPS) {
        spline_eval_pipe<TRIPS><<<grid, BLOCK, 0, stream>>>(x, points, values, out);
    } else {
        spline_eval_generic<<<grid, BLOCK, 0, stream>>>(x, points, values, out, n4, total);
    }
}

// Round 9
// 27.028 us; speedup vs baseline: 1.0234x; 1.0134x over previous
//
#include <hip/hip_runtime.h>

typedef float float4v __attribute__((ext_vector_type(4)));

#define BLOCK 256

// ---- tiny not-a-knot spline solve (tridiagonal -> Thomas), n = 10 ----
// SoA float2 tables: s32[i]={a3,a2}, s10[i]={a1,a0}; sm={scale,off} for the
// uniform-knot analytic interval index i = clamp(int(x*scale+off),0,8).
__device__ __forceinline__ void spline_setup(const float* __restrict__ points,
                                             const float* __restrict__ values,
                                             float2* s32, float2* s10, float* sm)
{
    float p[10], v[10];
#pragma unroll
    for (int k = 0; k < 10; ++k) { p[k] = points[k]; v[k] = values[k]; }
    float dx[9], sl[9];
#pragma unroll
    for (int k = 0; k < 9; ++k) { dx[k] = p[k + 1] - p[k]; sl[k] = (v[k + 1] - v[k]) / dx[k]; }

    float dg[10], lo[10], up[10], bb[10];
    float d0 = p[2] - p[0];
    dg[0] = dx[1]; up[0] = d0; lo[0] = 0.0f;
    bb[0] = ((dx[0] + 2.0f * d0) * dx[1] * sl[0] + dx[0] * dx[0] * sl[1]) / d0;
#pragma unroll
    for (int i = 1; i <= 8; ++i) {
        lo[i] = dx[i];
        dg[i] = 2.0f * (dx[i - 1] + dx[i]);
        up[i] = dx[i - 1];
        bb[i] = 3.0f * (dx[i] * sl[i - 1] + dx[i - 1] * sl[i]);
    }
    float dn = p[9] - p[7];
    lo[9] = dn; dg[9] = dx[7]; up[9] = 0.0f;
    bb[9] = (dx[8] * dx[8] * sl[7] + (2.0f * dn + dx[8]) * dx[7] * sl[8]) / dn;

    float cp[10], bp[10];
    cp[0] = up[0] / dg[0];
    bp[0] = bb[0] / dg[0];
#pragma unroll
    for (int i = 1; i <= 9; ++i) {
        float m = dg[i] - lo[i] * cp[i - 1];
        cp[i] = up[i] / m;
        bp[i] = (bb[i] - lo[i] * bp[i - 1]) / m;
    }
    float s[10];
    s[9] = bp[9];
#pragma unroll
    for (int i = 8; i >= 0; --i) s[i] = bp[i] - cp[i] * s[i + 1];

#pragma unroll
    for (int i = 0; i < 9; ++i) {
        float tt = (s[i] + s[i + 1] - 2.0f * sl[i]) / dx[i];
        float c3 = tt / dx[i];
        float c2 = (sl[i] - s[i]) / dx[i] - tt;
        float c1 = s[i];
        float c0 = v[i];
        float pi = p[i];
        float a3 = c3;
        float a2 = c2 - 3.0f * c3 * pi;
        float a1 = (3.0f * c3 * pi - 2.0f * c2) * pi + c1;
        float a0 = ((-c3 * pi + c2) * pi - c1) * pi + c0;
        s32[i] = make_float2(a3, a2);
        s10[i] = make_float2(a1, a0);
    }
    float scale = 9.0f / (p[9] - p[0]);
    sm[0] = scale;
    sm[1] = -p[0] * scale;
}

__device__ __forceinline__ float eval_one(float xx, float scale, float off,
                                          const float2* s32, const float2* s10)
{
    int i = (int)(xx * scale + off);   // trunc == floor in-range; clamp fixes edges
    i = i < 0 ? 0 : (i > 8 ? 8 : i);
    float2 h = s32[i];
    float2 l = s10[i];
    return ((h.x * xx + h.y) * xx + l.x) * xx + l.y;
}

// Exact-fit path: n4 == gridDim.x * BLOCK * TRIPS. Rolling loop with 2-stage
// software pipeline: trip k+1's load is issued before trip k's compute+store,
// keeping ~2 loads in flight per wave. First load issued before the setup
// barrier so it overlaps thread0's solve.
// Measured best (R6): 26.9 us = 5.0 TB/s = ~80% of the 6.29 TB/s copy
// ceiling. Depth 4 (R7) and 8-deep batch (R2) regress; NT load/store,
// register coefficient table (R8) neutral-to-worse. This is the local optimum.
template <int TRIPS>
__global__ __launch_bounds__(BLOCK) void spline_eval_pipe(
    const float* __restrict__ xin,
    const float* __restrict__ points,
    const float* __restrict__ values,
    float* __restrict__ out)
{
    __shared__ float2 s32[9];
    __shared__ float2 s10[9];
    __shared__ float sm[2];

    const float4v* __restrict__ x4 = (const float4v*)xin;
    float4v* __restrict__ o4 = (float4v*)out;

    const int stride = gridDim.x * BLOCK;
    int vi = blockIdx.x * BLOCK + threadIdx.x;

    float4v cur = x4[vi];              // in flight across the setup barrier

    if (threadIdx.x == 0) spline_setup(points, values, s32, s10, sm);
    __syncthreads();

    const float scale = sm[0], off = sm[1];

#pragma unroll
    for (int k = 0; k < TRIPS; ++k) {
        float4v nxt;
        if (k + 1 < TRIPS) nxt = x4[vi + stride];   // prefetch next trip
        float4v yv;
#pragma unroll
        for (int j = 0; j < 4; ++j)
            yv[j] = eval_one(cur[j], scale, off, s32, s10);
        o4[vi] = yv;
        vi += stride;
        cur = nxt;
    }
}

// Generic fallback: rolling grid-stride + scalar tail.
__global__ __launch_bounds__(BLOCK) void spline_eval_generic(
    const float* __restrict__ xin,
    const float* __restrict__ points,
    const float* __restrict__ values,
    float* __restrict__ out,
    int n4, int total)
{
    __shared__ float2 s32[9];
    __shared__ float2 s10[9];
    __shared__ float sm[2];

    if (threadIdx.x == 0) spline_setup(points, values, s32, s10, sm);
    __syncthreads();

    const float scale = sm[0], off = sm[1];

    const float4v* __restrict__ x4 = (const float4v*)xin;
    float4v* __restrict__ o4 = (float4v*)out;

    int idx = blockIdx.x * blockDim.x + threadIdx.x;
    int stride = gridDim.x * blockDim.x;

    for (int vi = idx; vi < n4; vi += stride) {
        float4v xv = x4[vi];
        float4v yv;
#pragma unroll
        for (int j = 0; j < 4; ++j)
            yv[j] = eval_one(xv[j], scale, off, s32, s10);
        o4[vi] = yv;
    }

    int tail = n4 * 4;
    if (blockIdx.x == 0) {
        for (int e = tail + threadIdx.x; e < total; e += blockDim.x) {
            out[e] = eval_one(xin[e], scale, off, s32, s10);
        }
    }
}

extern "C" void kernel_launch(void* const* d_in, const int* in_sizes, int n_in,
                              void* d_out, int out_size, void* d_ws, size_t ws_size,
                              hipStream_t stream) {
    const float* x = (const float*)d_in[0];
    const float* points = (const float*)d_in[1];
    const float* values = (const float*)d_in[2];
    float* out = (float*)d_out;

    int total = out_size;              // 4096*4096 = 16777216
    int n4 = total / 4;

    const int TRIPS = 8;
    const int grid = 2048;             // 8 blocks/CU

    if (total % 4 == 0 && n4 == grid * BLOCK * TRIPS) {
        spline_eval_pipe<TRIPS><<<grid, BLOCK, 0, stream>>>(x, points, values, out);
    } else {
        spline_eval_generic<<<grid, BLOCK, 0, stream>>>(x, points, values, out, n4, total);
    }
}